// Round 1
// baseline (766.220 us; speedup 1.0000x reference)
//
#include <hip/hip_runtime.h>

#define NPIX 4096
#define CCH  64
#define ADIM 8

// d_ws layout (floats):
//   q : [B][N][A]  @ 0        (262144)   row n's 8 q values contiguous
//   k : [B][A][N]  @ 262144   (262144)   m contiguous per a
//   vT: [B][N][C]  @ 524288   (2097152)  c contiguous per m  (coalesced PV reads)
// total 2,621,440 floats = 10.5 MB

__global__ __launch_bounds__(256) void qkv_kernel(
    const float* __restrict__ x,
    const float* __restrict__ Wq, const float* __restrict__ bq,
    const float* __restrict__ Wk, const float* __restrict__ bk,
    const float* __restrict__ Wv, const float* __restrict__ bv,
    float* __restrict__ ws)
{
    __shared__ float xs[64][64];              // [c][n_local]
    const int t  = threadIdx.x;
    const int b  = blockIdx.x >> 6;           // 64 n-tiles per batch
    const int n0 = (blockIdx.x & 63) << 6;    // 64 pixels per block
    const float* xb = x + ((size_t)b * CCH) * NPIX;

    #pragma unroll
    for (int ii = 0; ii < 16; ++ii) {
        int idx = t + (ii << 8);              // 0..4095
        int c = idx >> 6, nl = idx & 63;
        xs[c][nl] = xb[(size_t)c * NPIX + n0 + nl];
    }
    __syncthreads();

    const int nl = t & 63;
    const int og = t >> 6;                    // 0..3 (wave-uniform)
    float* qw = ws;
    float* kw = ws + 262144;
    float* vw = ws + 524288;
    const int n = n0 + nl;

    for (int oo = 0; oo < 20; ++oo) {
        const int o = og * 20 + oo;           // 0..79: 0-7 q, 8-15 k, 16-79 v
        const float* Wrow;
        float bias;
        if (o < 8)       { Wrow = Wq + o * CCH;        bias = bq[o]; }
        else if (o < 16) { Wrow = Wk + (o - 8) * CCH;  bias = bk[o - 8]; }
        else             { Wrow = Wv + (o - 16) * CCH; bias = bv[o - 16]; }
        float acc = bias;
        #pragma unroll
        for (int c = 0; c < CCH; ++c) acc += Wrow[c] * xs[c][nl];
        if (o < 8)       qw[((size_t)b * NPIX + n) * ADIM + o] = acc;
        else if (o < 16) kw[((size_t)b * ADIM + (o - 8)) * NPIX + n] = acc;
        else             vw[((size_t)b * NPIX + n) * CCH + (o - 16)] = acc;
    }
}

// One block = 256 threads = 32 attention rows of one batch.
// Phase 1: row softmax denominators (no max subtraction: |energy| < ~4, f32-safe).
// Phase 2 (per 256-m chunk): recompute energy, write normalized P (global + LDS),
// then PV GEMM (4r x 4c register tile, m split across two thread-halves).
// Epilogue: attn_out / feature_delta / LayerNorm(channel) fused.
__global__ __launch_bounds__(256) void attn_kernel(
    const float* __restrict__ x, const float* __restrict__ ws,
    const float* __restrict__ gamma_p,
    const float* __restrict__ ln_w, const float* __restrict__ ln_b,
    float* __restrict__ out, float* __restrict__ attn,
    float* __restrict__ fd_out, float* __restrict__ ao_out)
{
    __shared__ float qs[32][8];
    __shared__ float rinv[32];
    __shared__ __align__(16) float ps[32][256];   // P chunk [row][m_in_chunk]
    __shared__ float O_lds[64][33];               // [c][row], +1 pad
    __shared__ float mu[32], rsig[32];

    const int t  = threadIdx.x;
    const int b  = blockIdx.x >> 7;               // 128 row-tiles per batch
    const int n0 = (blockIdx.x & 127) << 5;       // 32 rows

    const float* qw = ws;
    const float* kw = ws + 262144;
    const float* vw = ws + 524288;
    const float* kb = kw + (size_t)b * ADIM * NPIX;

    {   // q tile -> LDS (coalesced)
        int r = t >> 3, a = t & 7;
        qs[r][a] = qw[((size_t)b * NPIX + n0 + r) * ADIM + a];
    }
    __syncthreads();

    const int rb = t >> 5;                        // 0..7: row-quad
    const int ml = t & 31;                        // m lane (stride-32 coverage)

    float qreg[4][8];
    #pragma unroll
    for (int rr = 0; rr < 4; ++rr)
        #pragma unroll
        for (int a = 0; a < 8; ++a)
            qreg[rr][a] = qs[rb * 4 + rr][a];

    // ---- phase 1: denominators ----
    float s4[4] = {0.f, 0.f, 0.f, 0.f};
    for (int j = 0; j < 128; ++j) {
        const int m = ml + (j << 5);
        float ka[8];
        #pragma unroll
        for (int a = 0; a < 8; ++a) ka[a] = kb[a * NPIX + m];
        #pragma unroll
        for (int rr = 0; rr < 4; ++rr) {
            float e = 0.f;
            #pragma unroll
            for (int a = 0; a < 8; ++a) e += qreg[rr][a] * ka[a];
            s4[rr] += __expf(e);
        }
    }
    #pragma unroll
    for (int off = 1; off < 32; off <<= 1) {
        #pragma unroll
        for (int rr = 0; rr < 4; ++rr) s4[rr] += __shfl_xor(s4[rr], off);
    }
    if (ml == 0) {
        #pragma unroll
        for (int rr = 0; rr < 4; ++rr) rinv[rb * 4 + rr] = 1.f / s4[rr];
    }
    __syncthreads();
    float ri4[4];
    #pragma unroll
    for (int rr = 0; rr < 4; ++rr) ri4[rr] = rinv[rb * 4 + rr];

    // PV thread decomposition: 128 output tiles (8 row-quads x 16 col-quads),
    // two threads per tile split the m-range.
    const int half = t >> 7;                      // 0/1
    const int tile = t & 127;
    const int pc0  = (tile & 15) << 2;            // channel base (x4)
    const int prg  = tile >> 4;                   // row-quad
    const int hoff = half << 7;                   // 0 or 128 within chunk
    float acc[4][4] = {};

    float* attn_base = attn + ((size_t)b * NPIX + n0) * NPIX;

    for (int mc = 0; mc < 16; ++mc) {
        const int m0 = mc << 8;
        // ---- sub-phase A: P for this chunk ----
        for (int j = 0; j < 8; ++j) {
            const int m = ml + (j << 5);
            float ka[8];
            #pragma unroll
            for (int a = 0; a < 8; ++a) ka[a] = kb[a * NPIX + m0 + m];
            #pragma unroll
            for (int rr = 0; rr < 4; ++rr) {
                float e = 0.f;
                #pragma unroll
                for (int a = 0; a < 8; ++a) e += qreg[rr][a] * ka[a];
                const float p = __expf(e) * ri4[rr];
                attn_base[(size_t)(rb * 4 + rr) * NPIX + m0 + m] = p;  // coalesced 128B runs
                ps[rb * 4 + rr][m] = p;                                 // conflict-free (stride-32 lanes)
            }
        }
        __syncthreads();
        // ---- sub-phase B: PV ----
        const float* vrow = vw + ((size_t)b * NPIX + m0 + hoff) * CCH + pc0;
        #pragma unroll 2
        for (int m4 = 0; m4 < 32; ++m4) {
            float pl[4][4];
            #pragma unroll
            for (int rr = 0; rr < 4; ++rr) {
                const float4 p4 = *(const float4*)&ps[prg * 4 + rr][hoff + (m4 << 2)];
                pl[rr][0] = p4.x; pl[rr][1] = p4.y; pl[rr][2] = p4.z; pl[rr][3] = p4.w;
            }
            #pragma unroll
            for (int qq = 0; qq < 4; ++qq) {
                const float4 vv = *(const float4*)(vrow + (size_t)((m4 << 2) + qq) * CCH);
                #pragma unroll
                for (int rr = 0; rr < 4; ++rr) {
                    acc[rr][0] += pl[rr][qq] * vv.x;
                    acc[rr][1] += pl[rr][qq] * vv.y;
                    acc[rr][2] += pl[rr][qq] * vv.z;
                    acc[rr][3] += pl[rr][qq] * vv.w;
                }
            }
        }
        __syncthreads();
    }

    // ---- merge the two m-halves into O_lds ----
    if (half == 0) {
        #pragma unroll
        for (int rr = 0; rr < 4; ++rr)
            #pragma unroll
            for (int cc = 0; cc < 4; ++cc)
                O_lds[pc0 + cc][prg * 4 + rr] = acc[rr][cc];
    }
    __syncthreads();
    if (half == 1) {
        #pragma unroll
        for (int rr = 0; rr < 4; ++rr)
            #pragma unroll
            for (int cc = 0; cc < 4; ++cc)
                O_lds[pc0 + cc][prg * 4 + rr] += acc[rr][cc];
    }
    __syncthreads();

    // ---- LN stats per row (8 lanes x 8 channels each) ----
    const float g = gamma_p[0];
    const float* xb = x + (size_t)b * CCH * NPIX + n0;
    {
        const int r = t >> 3, l8 = t & 7;
        float sum = 0.f, sum2 = 0.f;
        #pragma unroll
        for (int cc = 0; cc < 8; ++cc) {
            const int c = l8 + (cc << 3);
            const float pre = xb[(size_t)c * NPIX + r] + g * O_lds[c][r];
            sum += pre; sum2 += pre * pre;
        }
        #pragma unroll
        for (int off = 1; off < 8; off <<= 1) {
            sum  += __shfl_xor(sum, off);
            sum2 += __shfl_xor(sum2, off);
        }
        if (l8 == 0) {
            const float m_ = sum * (1.f / 64.f);
            const float v_ = sum2 * (1.f / 64.f) - m_ * m_;
            mu[r]   = m_;
            rsig[r] = rsqrtf(v_ + 1e-5f);
        }
    }
    __syncthreads();

    // ---- write attn_out / feature_delta / out (coalesced 128B runs) ----
    #pragma unroll
    for (int ii = 0; ii < 8; ++ii) {
        const int idx = t + (ii << 8);            // 0..2047 = 64c x 32n
        const int c = idx >> 5, nl = idx & 31;
        const float o   = O_lds[c][nl];
        const float fdv = g * o;
        const float pre = xb[(size_t)c * NPIX + nl] + fdv;
        const float y   = (pre - mu[nl]) * rsig[nl] * ln_w[c] + ln_b[c];
        const size_t off = (size_t)b * CCH * NPIX + (size_t)c * NPIX + n0 + nl;
        ao_out[off] = o;
        fd_out[off] = fdv;
        out[off]    = y;
    }
}

extern "C" void kernel_launch(void* const* d_in, const int* in_sizes, int n_in,
                              void* d_out, int out_size, void* d_ws, size_t ws_size,
                              hipStream_t stream) {
    const float* x     = (const float*)d_in[0];
    const float* Wq    = (const float*)d_in[1];
    const float* bq    = (const float*)d_in[2];
    const float* Wk    = (const float*)d_in[3];
    const float* bk    = (const float*)d_in[4];
    const float* Wv    = (const float*)d_in[5];
    const float* bv    = (const float*)d_in[6];
    const float* gamma = (const float*)d_in[7];
    const float* lnw   = (const float*)d_in[8];
    const float* lnb   = (const float*)d_in[9];

    float* out  = (float*)d_out;                  // [8,64,64,64]
    float* attn = out + 2097152;                  // [8,4096,4096]
    float* fd   = out + 136314880;                // [8,64,64,64]
    float* ao   = out + 138412032;                // [8,64,64,64]
    float* ws   = (float*)d_ws;                   // needs 10.5 MB

    qkv_kernel<<<512, 256, 0, stream>>>(x, Wq, bq, Wk, bk, Wv, bv, ws);
    attn_kernel<<<1024, 256, 0, stream>>>(x, ws, gamma, lnw, lnb, out, attn, fd, ao);
}

// Round 3
// 552.532 us; speedup vs baseline: 1.3867x; 1.3867x over previous
//
#include <hip/hip_runtime.h>

#define NPIX 4096
#define CCH  64

typedef __attribute__((ext_vector_type(8))) short bf16x8;
typedef __attribute__((ext_vector_type(4))) float f32x4;

static __device__ __forceinline__ unsigned short f2bf(float f) {
    union { float f; unsigned u; } v; v.f = f;
    unsigned r = (v.u + 0x7FFFu + ((v.u >> 16) & 1u)) >> 16;
    return (unsigned short)r;
}

// d_ws layout:
//   q     : [B][N][8]  f32 @ float 0        (262144 floats)
//   kT    : [B][N][8]  f32 @ float 262144   (262144 floats)
//   vfrag : [B][kc=128][ct=4][lane=64][8] bf16 @ float 524288 (2M ushorts = 4MB)
// vfrag is the exact B-fragment order for mfma_f32_16x16x32_bf16:
//   B[k][col] = V[m = kc*32 + (lane>>4)*8 + j][c = ct*16 + (lane&15)]

__global__ __launch_bounds__(256) void qkv_kernel(
    const float* __restrict__ x,
    const float* __restrict__ Wq, const float* __restrict__ bq,
    const float* __restrict__ Wk, const float* __restrict__ bk,
    const float* __restrict__ Wv, const float* __restrict__ bv,
    float* __restrict__ ws)
{
    __shared__ float xs[64][64];              // [c][n_local]
    const int t  = threadIdx.x;
    const int b  = blockIdx.x >> 6;           // 64 n-tiles per batch
    const int n0 = (blockIdx.x & 63) << 6;    // 64 pixels per block
    const float* xb = x + ((size_t)b * CCH) * NPIX;

    #pragma unroll
    for (int ii = 0; ii < 16; ++ii) {
        int idx = t + (ii << 8);              // 0..4095
        int c = idx >> 6, nl = idx & 63;
        xs[c][nl] = xb[(size_t)c * NPIX + n0 + nl];
    }
    __syncthreads();

    const int nl = t & 63;
    const int og = t >> 6;                    // 0..3 (wave-uniform)
    float* qw = ws;
    float* kw = ws + 262144;
    unsigned short* vf = (unsigned short*)(ws + 524288);
    const int n = n0 + nl;

    for (int oo = 0; oo < 20; ++oo) {
        const int o = og * 20 + oo;           // 0..79: 0-7 q, 8-15 k, 16-79 v
        const float* Wrow;
        float bias;
        if (o < 8)       { Wrow = Wq + o * CCH;        bias = bq[o]; }
        else if (o < 16) { Wrow = Wk + (o - 8) * CCH;  bias = bk[o - 8]; }
        else             { Wrow = Wv + (o - 16) * CCH; bias = bv[o - 16]; }
        float acc = bias;
        #pragma unroll
        for (int c = 0; c < CCH; ++c) acc += Wrow[c] * xs[c][nl];
        if (o < 8)       qw[((size_t)b * NPIX + n) * 8 + o] = acc;
        else if (o < 16) kw[((size_t)b * NPIX + n) * 8 + (o - 8)] = acc;
        else {
            const int c  = o - 16;
            const int kc = n >> 5, r5 = n & 31;
            const int lane = ((r5 >> 3) << 4) | (c & 15);
            const size_t idx = ((((size_t)b * 128 + kc) * 4 + (c >> 4)) * 64 + lane) * 8 + (r5 & 7);
            vf[idx] = f2bf(acc);
        }
    }
}

// One block = 256 threads (4 waves) = 32 attention rows of one batch.
// Thread (t): qr = t>>4 owns rows {qr, qr+16}; ml = t&15 owns m-quads ml*4 + j*64.
// Phase 1: denominators (energy+exp, no max subtraction: |e| < ~4, f32-safe).
// Main loop over 16 m-chunks of 256:
//   Phase A (all threads): e, p = exp(e)/denom; float4 store to attention;
//                          bf16-pack into XOR-swizzled LDS psb.
//   Phase B (per wave = 16-channel tile): A-frags from psb (ds_read_b128,
//                          conflict-free via swizzle), B-frags from vfrag
//                          (coalesced dwordx4), 2x mfma_f32_16x16x32_bf16.
// Epilogue: attn_out / feature_delta / channel-LayerNorm fused.
__global__ __launch_bounds__(256) void attn_kernel(
    const float* __restrict__ x, const float* __restrict__ ws,
    const float* __restrict__ gamma_p,
    const float* __restrict__ ln_w, const float* __restrict__ ln_b,
    float* __restrict__ out, float* __restrict__ attn,
    float* __restrict__ fd_out, float* __restrict__ ao_out)
{
    __shared__ __align__(16) unsigned short psb[32 * 256];  // swizzled bf16 P chunk
    __shared__ float O_lds[64][33];
    __shared__ float mu[32], rsig[32];

    const int t  = threadIdx.x;
    const int b  = blockIdx.x >> 7;               // 128 row-tiles per batch
    const int n0 = (blockIdx.x & 127) << 5;       // 32 rows

    const float* qw = ws;
    const float* kw = ws + 262144;
    const unsigned short* vf = (const unsigned short*)(ws + 524288);

    const int qr = t >> 4;                        // 0..15
    const int ml = t & 15;                        // m-quad lane

    // q for rows qr and qr+16 (L1-broadcast across the 16 lanes of a group)
    float q0[8], q1[8];
    {
        const float* qp0 = qw + ((size_t)b * NPIX + n0 + qr) * 8;
        const float* qp1 = qp0 + 16 * 8;
        #pragma unroll
        for (int a = 0; a < 8; ++a) { q0[a] = qp0[a]; q1[a] = qp1[a]; }
    }
    const float* kb = kw + (size_t)b * NPIX * 8;

    // ---- phase 1: softmax denominators ----
    float s0 = 0.f, s1 = 0.f;
    for (int j = 0; j < 64; ++j) {
        const int mq = (ml << 2) + (j << 6);
        const float4* kp = (const float4*)(kb + (size_t)mq * 8);
        #pragma unroll
        for (int i = 0; i < 4; ++i) {
            const float4 ka = kp[2 * i], kc2 = kp[2 * i + 1];
            float e0 = q0[0]*ka.x + q0[1]*ka.y + q0[2]*ka.z + q0[3]*ka.w
                     + q0[4]*kc2.x + q0[5]*kc2.y + q0[6]*kc2.z + q0[7]*kc2.w;
            float e1 = q1[0]*ka.x + q1[1]*ka.y + q1[2]*ka.z + q1[3]*ka.w
                     + q1[4]*kc2.x + q1[5]*kc2.y + q1[6]*kc2.z + q1[7]*kc2.w;
            s0 += __expf(e0);
            s1 += __expf(e1);
        }
    }
    #pragma unroll
    for (int off = 1; off < 16; off <<= 1) {
        s0 += __shfl_xor(s0, off);
        s1 += __shfl_xor(s1, off);
    }
    const float ri0 = 1.f / s0, ri1 = 1.f / s1;

    // ---- main loop ----
    const int wv = t >> 6;                        // wave id = channel tile
    const int l  = t & 63;
    f32x4 acc0 = {0.f, 0.f, 0.f, 0.f};
    f32x4 acc1 = {0.f, 0.f, 0.f, 0.f};

    char* pbase = (char*)psb;
    const int sw   = (qr & 7) << 4;               // write-side swizzle (rows qr, qr+16 share it)
    // A-frag addressing: row = l&15 (acc0) / 16+(l&15) (acc1).
    // Stored P[row][m] lives at byte (m*2) ^ ((row&7)<<4) within the row.
    // Read offset must be ((kc8<<6) | acol) ^ sxor -- XOR fold, NOT add (bit-6 carry bug).
    const int arow0 = (l & 15) * 512;
    const int acol  = (l >> 4) << 4;
    const int sxor  = (l & 7) << 4;

    float* attn_base = attn + ((size_t)b * NPIX + n0) * NPIX;

    for (int mc = 0; mc < 16; ++mc) {
        const int m0 = mc << 8;
        // ---- phase A: P for this chunk ----
        #pragma unroll
        for (int j = 0; j < 4; ++j) {
            const int mq = m0 + (ml << 2) + (j << 6);
            const float4* kp = (const float4*)(kb + (size_t)mq * 8);
            float p0[4], p1[4];
            #pragma unroll
            for (int i = 0; i < 4; ++i) {
                const float4 ka = kp[2 * i], kc2 = kp[2 * i + 1];
                float e0 = q0[0]*ka.x + q0[1]*ka.y + q0[2]*ka.z + q0[3]*ka.w
                         + q0[4]*kc2.x + q0[5]*kc2.y + q0[6]*kc2.z + q0[7]*kc2.w;
                float e1 = q1[0]*ka.x + q1[1]*ka.y + q1[2]*ka.z + q1[3]*ka.w
                         + q1[4]*kc2.x + q1[5]*kc2.y + q1[6]*kc2.z + q1[7]*kc2.w;
                p0[i] = __expf(e0) * ri0;
                p1[i] = __expf(e1) * ri1;
            }
            float4 st0 = make_float4(p0[0], p0[1], p0[2], p0[3]);
            float4 st1 = make_float4(p1[0], p1[1], p1[2], p1[3]);
            *(float4*)(attn_base + (size_t)qr * NPIX + mq)        = st0;  // 256B/quarter-wave
            *(float4*)(attn_base + (size_t)(qr + 16) * NPIX + mq) = st1;
            // bf16 pack -> swizzled LDS
            const int moff = (ml << 3) + (j << 7);        // byte offset of m within row
            uint2 w0, w1;
            w0.x = (unsigned)f2bf(p0[0]) | ((unsigned)f2bf(p0[1]) << 16);
            w0.y = (unsigned)f2bf(p0[2]) | ((unsigned)f2bf(p0[3]) << 16);
            w1.x = (unsigned)f2bf(p1[0]) | ((unsigned)f2bf(p1[1]) << 16);
            w1.y = (unsigned)f2bf(p1[2]) | ((unsigned)f2bf(p1[3]) << 16);
            *(uint2*)(pbase + qr * 512        + (moff ^ sw)) = w0;
            *(uint2*)(pbase + (qr + 16) * 512 + (moff ^ sw)) = w1;
        }
        __syncthreads();
        // ---- phase B: PV via MFMA ----
        {
            const unsigned short* vbase = vf + (((size_t)b * 128 + (m0 >> 5)) * 4 + wv) * 512;
            #pragma unroll
            for (int kc8 = 0; kc8 < 8; ++kc8) {
                const int aoff = ((kc8 << 6) | acol) ^ sxor;   // XOR-folded (bug fix)
                const bf16x8 Bf = *(const bf16x8*)(vbase + (size_t)kc8 * 2048 + l * 8);
                const bf16x8 A0 = *(const bf16x8*)(pbase + arow0 + aoff);
                const bf16x8 A1 = *(const bf16x8*)(pbase + arow0 + 8192 + aoff);
                acc0 = __builtin_amdgcn_mfma_f32_16x16x32_bf16(A0, Bf, acc0, 0, 0, 0);
                acc1 = __builtin_amdgcn_mfma_f32_16x16x32_bf16(A1, Bf, acc1, 0, 0, 0);
            }
        }
        __syncthreads();
    }

    // ---- move accumulators to O_lds[c][row] ----
    {
        const int c  = (wv << 4) + (l & 15);
        const int r0 = (l >> 4) << 2;
        #pragma unroll
        for (int r = 0; r < 4; ++r) {
            O_lds[c][r0 + r]      = acc0[r];
            O_lds[c][16 + r0 + r] = acc1[r];
        }
    }
    __syncthreads();

    // ---- LN stats per row (8 lanes x 8 channels each) ----
    const float g = gamma_p[0];
    const float* xb = x + (size_t)b * CCH * NPIX + n0;
    {
        const int r = t >> 3, l8 = t & 7;
        float sum = 0.f, sum2 = 0.f;
        #pragma unroll
        for (int cc = 0; cc < 8; ++cc) {
            const int c = l8 + (cc << 3);
            const float pre = xb[(size_t)c * NPIX + r] + g * O_lds[c][r];
            sum += pre; sum2 += pre * pre;
        }
        #pragma unroll
        for (int off = 1; off < 8; off <<= 1) {
            sum  += __shfl_xor(sum, off);
            sum2 += __shfl_xor(sum2, off);
        }
        if (l8 == 0) {
            const float m_ = sum * (1.f / 64.f);
            const float v_ = sum2 * (1.f / 64.f) - m_ * m_;
            mu[r]   = m_;
            rsig[r] = rsqrtf(v_ + 1e-5f);
        }
    }
    __syncthreads();

    // ---- write attn_out / feature_delta / out (coalesced 128B runs) ----
    #pragma unroll
    for (int ii = 0; ii < 8; ++ii) {
        const int idx = t + (ii << 8);            // 0..2047 = 64c x 32n
        const int c = idx >> 5, nl = idx & 31;
        const float o   = O_lds[c][nl];
        const float fdv = g * o;
        const float pre = xb[(size_t)c * NPIX + nl] + fdv;
        const float y   = (pre - mu[nl]) * rsig[nl] * ln_w[c] + ln_b[c];
        const size_t off = (size_t)b * CCH * NPIX + (size_t)c * NPIX + n0 + nl;
        ao_out[off] = o;
        fd_out[off] = fdv;
        out[off]    = y;
    }
}

extern "C" void kernel_launch(void* const* d_in, const int* in_sizes, int n_in,
                              void* d_out, int out_size, void* d_ws, size_t ws_size,
                              hipStream_t stream) {
    const float* x     = (const float*)d_in[0];
    const float* Wq    = (const float*)d_in[1];
    const float* bq    = (const float*)d_in[2];
    const float* Wk    = (const float*)d_in[3];
    const float* bk    = (const float*)d_in[4];
    const float* Wv    = (const float*)d_in[5];
    const float* bv    = (const float*)d_in[6];
    const float* gamma = (const float*)d_in[7];
    const float* lnw   = (const float*)d_in[8];
    const float* lnb   = (const float*)d_in[9];

    float* out  = (float*)d_out;                  // [8,64,64,64]
    float* attn = out + 2097152;                  // [8,4096,4096]
    float* fd   = out + 136314880;                // [8,64,64,64]
    float* ao   = out + 138412032;                // [8,64,64,64]
    float* ws   = (float*)d_ws;                   // 6 MB used

    qkv_kernel<<<512, 256, 0, stream>>>(x, Wq, bq, Wk, bk, Wv, bv, ws);
    attn_kernel<<<1024, 256, 0, stream>>>(x, ws, gamma, lnw, lnb, out, attn, fd, ao);
}

// Round 4
// 228.131 us; speedup vs baseline: 3.3587x; 2.4220x over previous
//
#include <hip/hip_runtime.h>

#define NPIX 4096
#define CCH  64

typedef __attribute__((ext_vector_type(8))) short bf16x8;
typedef __attribute__((ext_vector_type(4))) float f32x4;

static __device__ __forceinline__ unsigned short f2bf(float f) {
    union { float f; unsigned u; } v; v.f = f;
    return (unsigned short)((v.u + 0x7FFFu + ((v.u >> 16) & 1u)) >> 16);
}

// ws layout (ushorts):
//   qf: [B][4096][8] bf16 @ 0         (512 KB)  Q rows, 16B each
//   kf: [B][4096][8] bf16 @ 262144    (512 KB)  K rows, 16B each
//   vf: [B][128 kc][4 ct][64 lane][8] bf16 @ 524288 (4 MB)
// vf is the exact B-fragment order for mfma_f32_16x16x32_bf16 (PV step):
//   B[k][col] = V[m = kc*32 + (lane>>4)*8 + j][c = ct*16 + (lane&15)]

__global__ __launch_bounds__(256) void qkv_kernel(
    const float* __restrict__ x,
    const float* __restrict__ Wq, const float* __restrict__ bq,
    const float* __restrict__ Wk, const float* __restrict__ bk,
    const float* __restrict__ Wv, const float* __restrict__ bv,
    unsigned short* __restrict__ ws)
{
    __shared__ float xs[64][64];              // [c][n_local]
    const int t  = threadIdx.x;
    const int b  = blockIdx.x >> 6;           // 64 n-tiles per batch
    const int n0 = (blockIdx.x & 63) << 6;    // 64 pixels per block
    const float* xb = x + ((size_t)b * CCH) * NPIX;

    #pragma unroll
    for (int ii = 0; ii < 16; ++ii) {
        int idx = t + (ii << 8);              // 0..4095
        int c = idx >> 6, nl = idx & 63;
        xs[c][nl] = xb[(size_t)c * NPIX + n0 + nl];
    }
    __syncthreads();

    const int nl = t & 63;
    const int og = t >> 6;                    // 0..3 (wave-uniform)
    unsigned short* qf = ws;
    unsigned short* kf = ws + 262144;
    unsigned short* vf = ws + 524288;
    const int n = n0 + nl;

    for (int oo = 0; oo < 20; ++oo) {
        const int o = og * 20 + oo;           // 0..79: 0-7 q, 8-15 k, 16-79 v
        const float* Wrow;
        float bias;
        if (o < 8)       { Wrow = Wq + o * CCH;        bias = bq[o]; }
        else if (o < 16) { Wrow = Wk + (o - 8) * CCH;  bias = bk[o - 8]; }
        else             { Wrow = Wv + (o - 16) * CCH; bias = bv[o - 16]; }
        float acc = bias;
        #pragma unroll
        for (int c = 0; c < CCH; ++c) acc += Wrow[c] * xs[c][nl];
        if (o < 8)       qf[((size_t)b * NPIX + n) * 8 + o] = f2bf(acc);
        else if (o < 16) kf[((size_t)b * NPIX + n) * 8 + (o - 8)] = f2bf(acc);
        else {
            const int c  = o - 16;
            const int kc = n >> 5, r5 = n & 31;
            const int lane = ((r5 >> 3) << 4) | (c & 15);
            const size_t idx = ((((size_t)b * 128 + kc) * 4 + (c >> 4)) * 64 + lane) * 8 + (r5 & 7);
            vf[idx] = f2bf(acc);
        }
    }
}

// One block = 256 threads (4 waves) = 32 attention rows of one batch.
// Energy via MFMA: A = Q rows (lanes<16, k=0..7; rest zero), B = K rows
// (lanes<16), K=32 zero-padded. C/D: col(m)=l&15, row=(l>>4)*4+r.
// Pass 1: row sums of exp(e) (MFMA e identical to pass 2 -> exact softmax).
// Pass 2 per 256-m chunk: wave w owns m-tiles w*4+j; exp*rinv -> nt-store
// f32 attention + bf16 scatter into XOR-swizzled psb; then PV MFMA (wave =
// 16-channel tile, A from psb, B from vf). Epilogue: LN fused.
__global__ __launch_bounds__(256) void attn_kernel(
    const float* __restrict__ x, const unsigned short* __restrict__ ws,
    const float* __restrict__ gamma_p,
    const float* __restrict__ ln_w, const float* __restrict__ ln_b,
    float* __restrict__ out, float* __restrict__ attn,
    float* __restrict__ fd_out, float* __restrict__ ao_out)
{
    __shared__ __align__(16) char smem[16384];   // psb | sred | O_lds+mu+rsig
    __shared__ float rinv[32];

    const int bid = blockIdx.x;
    const int wg  = ((bid & 7) << 7) | (bid >> 3);  // XCD-bijective: batch b -> XCD b
    const int b   = wg >> 7;
    const int n0  = (wg & 127) << 5;

    const unsigned short* qf = ws;
    const unsigned short* kf = ws + 262144;
    const unsigned short* vf = ws + 524288;

    const int t   = threadIdx.x;
    const int l   = t & 63;
    const int w   = t >> 6;                       // wave id
    const int g   = l >> 4;                       // subgroup 0..3
    const int c16 = l & 15;

    const unsigned short* qfb = qf + ((size_t)b * NPIX + n0) * 8;
    const unsigned short* kfb = kf + (size_t)b * NPIX * 8;
    const unsigned short* vfb = vf + (size_t)b * 128 * 2048;

    const f32x4 zf = {0.f, 0.f, 0.f, 0.f};

    // Q A-fragments (rows n0..n0+15 and n0+16..n0+31), zero for lanes >= 16
    bf16x8 QA0 = {}, QA1 = {};
    if (l < 16) {
        QA0 = *(const bf16x8*)(qfb + l * 8);
        QA1 = *(const bf16x8*)(qfb + (16 + l) * 8);
    }

    // ---- pass 1: softmax denominators ----
    float s0[4] = {0.f,0.f,0.f,0.f}, s1[4] = {0.f,0.f,0.f,0.f};
    #pragma unroll 4
    for (int mt = 0; mt < 64; ++mt) {
        const int mbase = (w << 10) + (mt << 4);
        bf16x8 Bk = {};
        if (l < 16) Bk = *(const bf16x8*)(kfb + (size_t)(mbase + l) * 8);
        f32x4 e0 = __builtin_amdgcn_mfma_f32_16x16x32_bf16(QA0, Bk, zf, 0, 0, 0);
        f32x4 e1 = __builtin_amdgcn_mfma_f32_16x16x32_bf16(QA1, Bk, zf, 0, 0, 0);
        #pragma unroll
        for (int r = 0; r < 4; ++r) {
            s0[r] += __expf(e0[r]);
            s1[r] += __expf(e1[r]);
        }
    }
    #pragma unroll
    for (int off = 1; off < 16; off <<= 1) {
        #pragma unroll
        for (int r = 0; r < 4; ++r) {
            s0[r] += __shfl_xor(s0[r], off);
            s1[r] += __shfl_xor(s1[r], off);
        }
    }
    {
        float* sred = (float*)smem;               // [w][g][8]
        if (c16 == 0) {
            #pragma unroll
            for (int r = 0; r < 4; ++r) {
                sred[(w * 4 + g) * 8 + r]     = s0[r];
                sred[(w * 4 + g) * 8 + 4 + r] = s1[r];
            }
        }
        __syncthreads();
        if (t < 32) {
            const int gg   = (t & 15) >> 2;
            const int slot = (t & 3) + ((t >> 4) << 2);
            float s = 0.f;
            #pragma unroll
            for (int ww = 0; ww < 4; ++ww) s += sred[(ww * 4 + gg) * 8 + slot];
            rinv[t] = 1.f / s;
        }
        __syncthreads();
    }

    float ri0[4], ri1[4];
    #pragma unroll
    for (int r = 0; r < 4; ++r) {
        ri0[r] = rinv[g * 4 + r];
        ri1[r] = rinv[16 + g * 4 + r];
    }

    // ---- main loop ----
    char* psb = smem;
    float* attn_base = attn + ((size_t)b * NPIX + n0) * NPIX;
    const int arow0 = c16 * 512;
    const int acol  = g << 4;
    const int sxor  = (l & 7) << 4;
    const unsigned short* vwave = vfb + w * 512;  // channel tile ct = w

    f32x4 acc0 = zf, acc1 = zf;

    for (int mc = 0; mc < 16; ++mc) {
        // ---- phase A: energy -> P for wave's 4 m-tiles ----
        #pragma unroll
        for (int j = 0; j < 4; ++j) {
            const int mloc = (w << 6) + (j << 4) + c16;   // m within chunk
            const int mg   = (mc << 8) + mloc;            // global m
            bf16x8 Bk = {};
            if (l < 16) Bk = *(const bf16x8*)(kfb + (size_t)((mc << 8) + (w << 6) + (j << 4) + l) * 8);
            f32x4 e0 = __builtin_amdgcn_mfma_f32_16x16x32_bf16(QA0, Bk, zf, 0, 0, 0);
            f32x4 e1 = __builtin_amdgcn_mfma_f32_16x16x32_bf16(QA1, Bk, zf, 0, 0, 0);
            #pragma unroll
            for (int r = 0; r < 4; ++r) {
                const int row0 = g * 4 + r, row1 = 16 + g * 4 + r;
                const float p0 = __expf(e0[r]) * ri0[r];
                const float p1 = __expf(e1[r]) * ri1[r];
                __builtin_nontemporal_store(p0, attn_base + (size_t)row0 * NPIX + mg);
                __builtin_nontemporal_store(p1, attn_base + (size_t)row1 * NPIX + mg);
                *(unsigned short*)(psb + row0 * 512 + ((mloc * 2) ^ ((row0 & 7) << 4))) = f2bf(p0);
                *(unsigned short*)(psb + row1 * 512 + ((mloc * 2) ^ ((row1 & 7) << 4))) = f2bf(p1);
            }
        }
        __syncthreads();
        // ---- phase B: PV via MFMA ----
        {
            const unsigned short* vbase = vwave + (size_t)(mc << 3) * 2048;
            #pragma unroll
            for (int kc8 = 0; kc8 < 8; ++kc8) {
                const int aoff = ((kc8 << 6) | acol) ^ sxor;
                const bf16x8 Bf = *(const bf16x8*)(vbase + (size_t)kc8 * 2048 + l * 8);
                const bf16x8 A0 = *(const bf16x8*)(psb + arow0 + aoff);
                const bf16x8 A1 = *(const bf16x8*)(psb + arow0 + 8192 + aoff);
                acc0 = __builtin_amdgcn_mfma_f32_16x16x32_bf16(A0, Bf, acc0, 0, 0, 0);
                acc1 = __builtin_amdgcn_mfma_f32_16x16x32_bf16(A1, Bf, acc1, 0, 0, 0);
            }
        }
        __syncthreads();
    }

    // ---- epilogue: O_lds aliases psb (dead after last barrier) ----
    float* O_lds = (float*)smem;                   // [64][33]
    float* muv   = (float*)(smem + 8448);          // [32]
    float* rsg   = (float*)(smem + 8576);          // [32]
    {
        const int ch = (w << 4) + c16;
        const int r0 = g << 2;
        #pragma unroll
        for (int r = 0; r < 4; ++r) {
            O_lds[ch * 33 + r0 + r]      = acc0[r];
            O_lds[ch * 33 + 16 + r0 + r] = acc1[r];
        }
    }
    __syncthreads();

    const float gma = gamma_p[0];
    const float* xb = x + (size_t)b * CCH * NPIX + n0;
    {
        const int r = t >> 3, l8 = t & 7;
        float sum = 0.f, sum2 = 0.f;
        #pragma unroll
        for (int cc = 0; cc < 8; ++cc) {
            const int c = l8 + (cc << 3);
            const float pre = xb[(size_t)c * NPIX + r] + gma * O_lds[c * 33 + r];
            sum += pre; sum2 += pre * pre;
        }
        #pragma unroll
        for (int off = 1; off < 8; off <<= 1) {
            sum  += __shfl_xor(sum, off);
            sum2 += __shfl_xor(sum2, off);
        }
        if (l8 == 0) {
            const float m_ = sum * (1.f / 64.f);
            const float v_ = sum2 * (1.f / 64.f) - m_ * m_;
            muv[r] = m_;
            rsg[r] = rsqrtf(v_ + 1e-5f);
        }
    }
    __syncthreads();

    #pragma unroll
    for (int ii = 0; ii < 8; ++ii) {
        const int idx = t + (ii << 8);             // 0..2047 = 64c x 32n
        const int c = idx >> 5, nl = idx & 31;
        const float o   = O_lds[c * 33 + nl];
        const float fdv = gma * o;
        const float pre = xb[(size_t)c * NPIX + nl] + fdv;
        const float y   = (pre - muv[nl]) * rsg[nl] * ln_w[c] + ln_b[c];
        const size_t off = (size_t)b * CCH * NPIX + (size_t)c * NPIX + n0 + nl;
        ao_out[off] = o;
        fd_out[off] = fdv;
        out[off]    = y;
    }
}

extern "C" void kernel_launch(void* const* d_in, const int* in_sizes, int n_in,
                              void* d_out, int out_size, void* d_ws, size_t ws_size,
                              hipStream_t stream) {
    const float* x     = (const float*)d_in[0];
    const float* Wq    = (const float*)d_in[1];
    const float* bq    = (const float*)d_in[2];
    const float* Wk    = (const float*)d_in[3];
    const float* bk    = (const float*)d_in[4];
    const float* Wv    = (const float*)d_in[5];
    const float* bv    = (const float*)d_in[6];
    const float* gamma = (const float*)d_in[7];
    const float* lnw   = (const float*)d_in[8];
    const float* lnb   = (const float*)d_in[9];

    float* out  = (float*)d_out;                  // [8,64,64,64]
    float* attn = out + 2097152;                  // [8,4096,4096]
    float* fd   = out + 136314880;                // [8,64,64,64]
    float* ao   = out + 138412032;                // [8,64,64,64]
    unsigned short* ws = (unsigned short*)d_ws;   // 5 MB used

    qkv_kernel<<<512, 256, 0, stream>>>(x, Wq, bq, Wk, bk, Wv, bv, ws);
    attn_kernel<<<1024, 256, 0, stream>>>(x, ws, gamma, lnw, lnb, out, attn, fd, ao);
}

// Round 5
// 171.005 us; speedup vs baseline: 4.4807x; 1.3341x over previous
//
#include <hip/hip_runtime.h>

#define NPIX 4096
#define CCH  64

typedef __attribute__((ext_vector_type(8))) short bf16x8;
typedef __attribute__((ext_vector_type(4))) float f32x4;

static __device__ __forceinline__ unsigned short f2bf(float f) {
    union { float f; unsigned u; } v; v.f = f;
    return (unsigned short)((v.u + 0x7FFFu + ((v.u >> 16) & 1u)) >> 16);
}
static __device__ __forceinline__ float bf2f_lo(unsigned u) {
    union { unsigned u; float f; } v; v.u = u << 16; return v.f;
}
static __device__ __forceinline__ float bf2f_hi(unsigned u) {
    union { unsigned u; float f; } v; v.u = u & 0xFFFF0000u; return v.f;
}

// ws layout (ushorts):
//   qf: [B][4096][8] bf16 @ 0         Q rows, 16B each
//   kf: [B][4096][8] bf16 @ 262144    K rows, 16B each
//   vf: [B][128 kc][4 ct][64 lane][8] bf16 @ 524288
// vf is the exact B-fragment order for mfma_f32_16x16x32_bf16 (PV step):
//   B[k][col] = V[m = kc*32 + (lane>>4)*8 + j][c = ct*16 + (lane&15)]

__global__ __launch_bounds__(256) void qkv_kernel(
    const float* __restrict__ x,
    const float* __restrict__ Wq, const float* __restrict__ bq,
    const float* __restrict__ Wk, const float* __restrict__ bk,
    const float* __restrict__ Wv, const float* __restrict__ bv,
    unsigned short* __restrict__ ws)
{
    __shared__ float xs[64][64];              // [c][n_local]
    const int t  = threadIdx.x;
    const int b  = blockIdx.x >> 6;           // 64 n-tiles per batch
    const int n0 = (blockIdx.x & 63) << 6;    // 64 pixels per block
    const float* xb = x + ((size_t)b * CCH) * NPIX;

    #pragma unroll
    for (int ii = 0; ii < 16; ++ii) {
        int idx = t + (ii << 8);              // 0..4095
        int c = idx >> 6, nl = idx & 63;
        xs[c][nl] = xb[(size_t)c * NPIX + n0 + nl];
    }
    __syncthreads();

    const int nl = t & 63;
    const int og = t >> 6;                    // 0..3 (wave-uniform)
    unsigned short* qf = ws;
    unsigned short* kf = ws + 262144;
    unsigned short* vf = ws + 524288;
    const int n = n0 + nl;

    for (int oo = 0; oo < 20; ++oo) {
        const int o = og * 20 + oo;           // 0..79: 0-7 q, 8-15 k, 16-79 v
        const float* Wrow;
        float bias;
        if (o < 8)       { Wrow = Wq + o * CCH;        bias = bq[o]; }
        else if (o < 16) { Wrow = Wk + (o - 8) * CCH;  bias = bk[o - 8]; }
        else             { Wrow = Wv + (o - 16) * CCH; bias = bv[o - 16]; }
        float acc = bias;
        #pragma unroll
        for (int c = 0; c < CCH; ++c) acc += Wrow[c] * xs[c][nl];
        if (o < 8)       qf[((size_t)b * NPIX + n) * 8 + o] = f2bf(acc);
        else if (o < 16) kf[((size_t)b * NPIX + n) * 8 + (o - 8)] = f2bf(acc);
        else {
            const int c  = o - 16;
            const int kc = n >> 5, r5 = n & 31;
            const int lane = ((r5 >> 3) << 4) | (c & 15);
            const size_t idx = ((((size_t)b * 128 + kc) * 4 + (c >> 4)) * 64 + lane) * 8 + (r5 & 7);
            vf[idx] = f2bf(acc);
        }
    }
}

// One block = 256 threads (4 waves) = 32 attention rows of one batch.
// Energy TRANSPOSED via MFMA: eT = mfma(A=K-rows, B=Q-rows) so a lane holds
// 4 consecutive m for query row n=c16 -> 8B LDS P-writes, scalar rinv/lane.
// Pass 1: denominators. Main loop, double-buffered psb, 1 barrier/chunk:
//   region mc: [A(mc+1)->nxt  ||  B(mc): PV MFMA from cur  ||  S(mc): stream
//   cur -> f32 attention, 16B/lane coalesced nt]. Epilogue: LN fused.
__global__ __launch_bounds__(256) void attn_kernel(
    const float* __restrict__ x, const unsigned short* __restrict__ ws,
    const float* __restrict__ gamma_p,
    const float* __restrict__ ln_w, const float* __restrict__ ln_b,
    float* __restrict__ out, float* __restrict__ attn,
    float* __restrict__ fd_out, float* __restrict__ ao_out)
{
    __shared__ __align__(16) char psb0[16384];   // P chunk buffer 0 (bf16, swizzled)
    __shared__ __align__(16) char psb1[16384];   // P chunk buffer 1
    __shared__ float rinv[32];

    const int bid = blockIdx.x;
    const int wg  = ((bid & 7) << 7) | (bid >> 3);  // XCD-bijective swizzle
    const int b   = wg >> 7;
    const int n0  = (wg & 127) << 5;

    const unsigned short* qf = ws;
    const unsigned short* kf = ws + 262144;
    const unsigned short* vf = ws + 524288;

    const int t   = threadIdx.x;
    const int l   = t & 63;
    const int w   = t >> 6;                       // wave id
    const int g   = l >> 4;                       // subgroup 0..3
    const int c16 = l & 15;

    const unsigned short* qfb = qf + ((size_t)b * NPIX + n0) * 8;
    const unsigned short* kfb = kf + (size_t)b * NPIX * 8;
    const unsigned short* vwave = vf + (size_t)b * 128 * 2048 + w * 512;

    const f32x4 zf = {0.f, 0.f, 0.f, 0.f};

    // Q as B-fragments (rows n0..n0+15 / +16..+31), lanes >= 16 zero (k=8..31 pad)
    bf16x8 QB0 = {}, QB1 = {};
    if (l < 16) {
        QB0 = *(const bf16x8*)(qfb + l * 8);
        QB1 = *(const bf16x8*)(qfb + (16 + l) * 8);
    }

    // ---- pass 1: softmax denominators (eT: lane sums over its 4 m's for n=c16) ----
    float s0 = 0.f, s1 = 0.f;
    #pragma unroll 4
    for (int mt = 0; mt < 64; ++mt) {
        const int mbase = (w << 10) + (mt << 4);
        bf16x8 Kf = {};
        if (l < 16) Kf = *(const bf16x8*)(kfb + (size_t)(mbase + l) * 8);
        f32x4 e0 = __builtin_amdgcn_mfma_f32_16x16x32_bf16(Kf, QB0, zf, 0, 0, 0);
        f32x4 e1 = __builtin_amdgcn_mfma_f32_16x16x32_bf16(Kf, QB1, zf, 0, 0, 0);
        #pragma unroll
        for (int r = 0; r < 4; ++r) {
            s0 += __expf(e0[r]);
            s1 += __expf(e1[r]);
        }
    }
    s0 += __shfl_xor(s0, 16); s0 += __shfl_xor(s0, 32);
    s1 += __shfl_xor(s1, 16); s1 += __shfl_xor(s1, 32);
    {
        float* sred = (float*)psb0;
        if (l < 16) {
            sred[w * 32 + l]      = s0;
            sred[w * 32 + 16 + l] = s1;
        }
        __syncthreads();
        if (t < 32) {
            const float s = sred[t] + sred[32 + t] + sred[64 + t] + sred[96 + t];
            rinv[t] = 1.f / s;
        }
        __syncthreads();
    }
    const float ri0 = rinv[c16], ri1 = rinv[16 + c16];

    // ---- main loop ----
    const int swx = (c16 & 7) << 4;               // LDS swizzle (write & A-read)
    const int wjg = (w << 7) + (g << 3);          // P-write byte base (add j<<5)
    const int srow = (w << 3) + (l >> 3);         // S-phase: row 0..31
    const int ssw  = (srow & 7) << 4;
    const int srm  = (l & 7) << 3;                // S-phase byte base (add i<<6)
    float* attn_base = attn + ((size_t)b * NPIX + n0) * NPIX;
    float* arow = attn_base + (size_t)srow * NPIX + ((l & 7) << 2);

    f32x4 acc0 = zf, acc1 = zf;

#define PHASE_A(MC, BUF) do {                                                     \
    _Pragma("unroll")                                                             \
    for (int j = 0; j < 4; ++j) {                                                 \
        const int mg = ((MC) << 8) + (w << 6) + (j << 4);                         \
        bf16x8 Kf = {};                                                           \
        if (l < 16) Kf = *(const bf16x8*)(kfb + (size_t)(mg + l) * 8);            \
        f32x4 e0 = __builtin_amdgcn_mfma_f32_16x16x32_bf16(Kf, QB0, zf, 0, 0, 0); \
        f32x4 e1 = __builtin_amdgcn_mfma_f32_16x16x32_bf16(Kf, QB1, zf, 0, 0, 0); \
        uint2 pk0, pk1;                                                           \
        pk0.x = (unsigned)f2bf(__expf(e0[0]) * ri0) | ((unsigned)f2bf(__expf(e0[1]) * ri0) << 16); \
        pk0.y = (unsigned)f2bf(__expf(e0[2]) * ri0) | ((unsigned)f2bf(__expf(e0[3]) * ri0) << 16); \
        pk1.x = (unsigned)f2bf(__expf(e1[0]) * ri1) | ((unsigned)f2bf(__expf(e1[1]) * ri1) << 16); \
        pk1.y = (unsigned)f2bf(__expf(e1[2]) * ri1) | ((unsigned)f2bf(__expf(e1[3]) * ri1) << 16); \
        const int wo = (wjg + (j << 5)) ^ swx;                                    \
        *(uint2*)((BUF) + c16 * 512 + wo)        = pk0;                           \
        *(uint2*)((BUF) + (16 + c16) * 512 + wo) = pk1;                           \
    }                                                                             \
} while (0)

#define PHASE_B(MC, BUF) do {                                                     \
    const unsigned short* vbase = vwave + ((size_t)(MC) << 14);                   \
    __builtin_amdgcn_s_setprio(1);                                                \
    _Pragma("unroll")                                                             \
    for (int kc8 = 0; kc8 < 8; ++kc8) {                                           \
        const int aoff = ((kc8 << 6) | (g << 4)) ^ swx;                           \
        const bf16x8 Bf = *(const bf16x8*)(vbase + (size_t)kc8 * 2048 + l * 8);   \
        const bf16x8 A0 = *(const bf16x8*)((BUF) + c16 * 512 + aoff);             \
        const bf16x8 A1 = *(const bf16x8*)((BUF) + c16 * 512 + 8192 + aoff);      \
        acc0 = __builtin_amdgcn_mfma_f32_16x16x32_bf16(A0, Bf, acc0, 0, 0, 0);    \
        acc1 = __builtin_amdgcn_mfma_f32_16x16x32_bf16(A1, Bf, acc1, 0, 0, 0);    \
    }                                                                             \
    __builtin_amdgcn_s_setprio(0);                                                \
} while (0)

#define PHASE_S(MC, BUF) do {                                                     \
    _Pragma("unroll")                                                             \
    for (int i = 0; i < 8; ++i) {                                                 \
        const int ro = (srm + (i << 6)) ^ ssw;                                    \
        const uint2 rv = *(const uint2*)((BUF) + srow * 512 + ro);                \
        f32x4 fv;                                                                 \
        fv[0] = bf2f_lo(rv.x); fv[1] = bf2f_hi(rv.x);                             \
        fv[2] = bf2f_lo(rv.y); fv[3] = bf2f_hi(rv.y);                             \
        __builtin_nontemporal_store(fv, (f32x4*)(arow + ((MC) << 8) + (i << 5))); \
    }                                                                             \
} while (0)

    PHASE_A(0, psb0);
    __syncthreads();
    #pragma unroll 2
    for (int mc = 0; mc < 16; ++mc) {
        char* cur = (mc & 1) ? psb1 : psb0;
        char* nxt = (mc & 1) ? psb0 : psb1;
        if (mc < 15) PHASE_A(mc + 1, nxt);
        PHASE_B(mc, cur);
        PHASE_S(mc, cur);
        __syncthreads();
    }

    // ---- epilogue: O_lds aliases psb0 (dead after last barrier) ----
    float* O_lds = (float*)psb0;                   // [64][33]
    float* muv   = (float*)(psb0 + 8448);          // [32]
    float* rsg   = (float*)(psb0 + 8576);          // [32]
    {
        const int ch = (w << 4) + c16;
        const int r0 = g << 2;
        #pragma unroll
        for (int r = 0; r < 4; ++r) {
            O_lds[ch * 33 + r0 + r]      = acc0[r];
            O_lds[ch * 33 + 16 + r0 + r] = acc1[r];
        }
    }
    __syncthreads();

    const float gma = gamma_p[0];
    const float* xb = x + (size_t)b * CCH * NPIX + n0;
    {
        const int r = t >> 3, l8 = t & 7;
        float sum = 0.f, sum2 = 0.f;
        #pragma unroll
        for (int cc = 0; cc < 8; ++cc) {
            const int c = l8 + (cc << 3);
            const float pre = xb[(size_t)c * NPIX + r] + gma * O_lds[c * 33 + r];
            sum += pre; sum2 += pre * pre;
        }
        #pragma unroll
        for (int off = 1; off < 8; off <<= 1) {
            sum  += __shfl_xor(sum, off);
            sum2 += __shfl_xor(sum2, off);
        }
        if (l8 == 0) {
            const float m_ = sum * (1.f / 64.f);
            const float v_ = sum2 * (1.f / 64.f) - m_ * m_;
            muv[r] = m_;
            rsg[r] = rsqrtf(v_ + 1e-5f);
        }
    }
    __syncthreads();

    #pragma unroll
    for (int ii = 0; ii < 8; ++ii) {
        const int idx = t + (ii << 8);             // 0..2047 = 64c x 32n
        const int c = idx >> 5, nl = idx & 31;
        const float o   = O_lds[c * 33 + nl];
        const float fdv = gma * o;
        const float pre = xb[(size_t)c * NPIX + nl] + fdv;
        const float y   = (pre - muv[nl]) * rsg[nl] * ln_w[c] + ln_b[c];
        const size_t off = (size_t)b * CCH * NPIX + (size_t)c * NPIX + n0 + nl;
        ao_out[off] = o;
        fd_out[off] = fdv;
        out[off]    = y;
    }
}

extern "C" void kernel_launch(void* const* d_in, const int* in_sizes, int n_in,
                              void* d_out, int out_size, void* d_ws, size_t ws_size,
                              hipStream_t stream) {
    const float* x     = (const float*)d_in[0];
    const float* Wq    = (const float*)d_in[1];
    const float* bq    = (const float*)d_in[2];
    const float* Wk    = (const float*)d_in[3];
    const float* bk    = (const float*)d_in[4];
    const float* Wv    = (const float*)d_in[5];
    const float* bv    = (const float*)d_in[6];
    const float* gamma = (const float*)d_in[7];
    const float* lnw   = (const float*)d_in[8];
    const float* lnb   = (const float*)d_in[9];

    float* out  = (float*)d_out;                  // [8,64,64,64]
    float* attn = out + 2097152;                  // [8,4096,4096]
    float* fd   = out + 136314880;                // [8,64,64,64]
    float* ao   = out + 138412032;                // [8,64,64,64]
    unsigned short* ws = (unsigned short*)d_ws;   // 5 MB used

    qkv_kernel<<<512, 256, 0, stream>>>(x, Wq, bq, Wk, bk, Wv, bv, ws);
    attn_kernel<<<1024, 256, 0, stream>>>(x, ws, gamma, lnw, lnb, out, attn, fd, ao);
}